// Round 3
// baseline (173.574 us; speedup 1.0000x reference)
//
#include <hip/hip_runtime.h>

// ---------------------------------------------------------------------------
// CostVolume fused kernel, R3: 2 blocks/CU occupancy.
//  - weights read directly from global d_ws (L2-hot, shared by all blocks),
//    stage-invariant packs hoisted to registers
//  - 2 LDS activation buffers per wave (was 3)
//  - bias/comb from global; OUTB overlays F1B/F2B
//  -> LDS 78,848 B => 2 blocks/CU, 8 waves/CU, 2 waves/SIMD
// ---------------------------------------------------------------------------

typedef __attribute__((ext_vector_type(8))) short   short8;
typedef __attribute__((ext_vector_type(8))) __bf16  bf16x8;
typedef __attribute__((ext_vector_type(4))) float   f32x4;
typedef __attribute__((ext_vector_type(4))) float   float4v;
typedef __attribute__((ext_vector_type(2))) unsigned int uint2v;

#define S_LEN 8192
#define TPB   256

// ---- workspace byte offsets (written by pack_weights) ----
// B-fragment packs: L11 @0, L20 @8192 (16KB), L21 @24576, L30A @32768,
// L31 @40960, WF1 @49152, WF2 @57344, W30B @65536, W30C @73728
#define WSO_L11   0
#define WSO_L20   8192
#define WSO_L21   24576
#define WSO_L30A  32768
#define WSO_L31   40960
#define WS_WF1    49152
#define WS_WF2    57344
#define WS_W30B   65536
#define WS_W30C   73728
#define WS_F32    81920   // 1344 f32: x-combos (6*192) + we1/ee/ge (3*64)

// ---- LDS byte offsets ----
#define OFF_ACT   0       // 4 waves x 8192 (myA 4K, myB 4K) bf16 swizzled [32][64]
#define OFF_F1B   32768   // [32][64] bf16 swizzled
#define OFF_F2B   36864
#define OFF_OUTB  32768   // [32][64] f32 XOR-swizzled, overlays F1B/F2B (stage-2 only)
#define OFF_AGGB  40960   // [32][64] bf16 swizzled
#define OFF_A1F   45056   // [32][64] f32
#define OFF_A2F   53248
#define OFF_C1F   61440
#define OFF_C2F   69632
#define OFF_X1    77824   // [32][4] f32
#define OFF_X2    78336
#define LDS_TOTAL 78848

__device__ __forceinline__ unsigned short f2bf(float f){
  unsigned int u = __float_as_uint(f);
  u += 0x7fffu + ((u >> 16) & 1u);
  return (unsigned short)(u >> 16);
}
__device__ __forceinline__ float bf2f(unsigned short h){
  return __uint_as_float(((unsigned int)h) << 16);
}

// swizzled bf16 [rows][64] helpers: byte = (r*64+c)*2 ^ ((r&7)<<4)
__device__ __forceinline__ bf16x8 ldsA(const char* base, int r, int k){
  short8 a = *(const short8*)(base + ((((r << 6) + k) << 1) ^ ((r & 7) << 4)));
  return __builtin_bit_cast(bf16x8, a);
}
__device__ __forceinline__ void stBF(char* base, int r, int c, float v){
  *(unsigned short*)(base + ((((r << 6) + c) << 1) ^ ((r & 7) << 4))) = f2bf(v);
}
__device__ __forceinline__ float ldBF(const char* base, int r, int c){
  return bf2f(*(const unsigned short*)(base + ((((r << 6) + c) << 1) ^ ((r & 7) << 4))));
}
__device__ __forceinline__ void stBF4(char* base, int r, int c4, float4v v){
  uint2v u;
  u.x = (unsigned)f2bf(v.x) | ((unsigned)f2bf(v.y) << 16);
  u.y = (unsigned)f2bf(v.z) | ((unsigned)f2bf(v.w) << 16);
  *(uint2v*)(base + ((((r << 6) + c4) << 1) ^ ((r & 7) << 4))) = u;
}
// OUTB f32 [32][64], idx ^= (p&7)<<2 (4-way max conflict on read)
__device__ __forceinline__ int outb_idx(int p, int ch){
  return ((p << 6) + ch) ^ ((p & 7) << 2);
}

// K=64 GEMM over 16 rows (precompute phases), B read per use (global ok)
__device__ __forceinline__ void gemm_k64(f32x4 acc[4], const char* Asrc,
                                         const char* Bp, int rbase, int lane){
  const int r  = rbase + (lane & 15);
  const int kg = (lane >> 4) << 3;
#pragma unroll
  for (int kb = 0; kb < 2; ++kb){
    bf16x8 a = ldsA(Asrc, r, kb * 32 + kg);
#pragma unroll
    for (int cb = 0; cb < 4; ++cb){
      short8 braw = *(const short8*)(Bp + (((kb << 2) + cb) * 64 + lane) * 16);
      acc[cb] = __builtin_amdgcn_mfma_f32_16x16x32_bf16(
          a, __builtin_bit_cast(bf16x8, braw), acc[cb], 0, 0, 0);
    }
  }
}

// load one K=64 B-pack (8 fragments) into registers (src may be global)
__device__ __forceinline__ void load_B8(bf16x8 Breg[8], const char* Bp, int lane){
#pragma unroll
  for (int u = 0; u < 8; ++u)
    Breg[u] = __builtin_bit_cast(bf16x8,
        *(const short8*)(Bp + (u * 64 + lane) * 16));
}

// wave-local K=64 GEMM over the wave's 32 rows, B in registers
__device__ __forceinline__ void gemm32_k64(f32x4 acc[2][4], const char* Asrc,
                                           const bf16x8 Breg[8], int lane){
  const int kg = (lane >> 4) << 3;
#pragma unroll
  for (int t = 0; t < 2; ++t){
    const int r = t * 16 + (lane & 15);
#pragma unroll
    for (int kb = 0; kb < 2; ++kb){
      bf16x8 a = ldsA(Asrc, r, kb * 32 + kg);
#pragma unroll
      for (int cb = 0; cb < 4; ++cb)
        acc[t][cb] = __builtin_amdgcn_mfma_f32_16x16x32_bf16(
            a, Breg[kb * 4 + cb], acc[t][cb], 0, 0, 0);
    }
  }
}

__device__ __forceinline__ float red_max(float x){
  x = fmaxf(x, __shfl_xor(x, 16, 64));
  x = fmaxf(x, __shfl_xor(x, 32, 64));
  return x;
}
__device__ __forceinline__ float red_sum(float x){
  x += __shfl_xor(x, 16, 64);
  x += __shfl_xor(x, 32, 64);
  return x;
}

__global__ void pack_weights(const float* __restrict__ w10, const float* __restrict__ w11,
                             const float* __restrict__ wx1, const float* __restrict__ wx2,
                             const float* __restrict__ w20, const float* __restrict__ w21,
                             const float* __restrict__ w30, const float* __restrict__ w31,
                             unsigned char* __restrict__ ws)
{
  for (int i = blockIdx.x * blockDim.x + threadIdx.x; i < 42304;
       i += gridDim.x * blockDim.x){
    if (i < 40960){
      const float* src; int stride, coff, e;
      if      (i <  4096){ src = w11; stride =  64; coff =   0; e = i;         }
      else if (i < 12288){ src = w20; stride = 128; coff =   0; e = i -  4096; }
      else if (i < 16384){ src = w21; stride =  64; coff =   0; e = i - 12288; }
      else if (i < 20480){ src = w30; stride = 192; coff =   0; e = i - 16384; }
      else if (i < 24576){ src = w31; stride =  64; coff =   0; e = i - 20480; }
      else if (i < 28672){ src = w10; stride = 138; coff =  10; e = i - 24576; }
      else if (i < 32768){ src = w10; stride = 138; coff =  74; e = i - 28672; }
      else if (i < 36864){ src = w30; stride = 192; coff =  64; e = i - 32768; }
      else               { src = w30; stride = 192; coff = 128; e = i - 36864; }
      int j = e & 7, lane = (e >> 3) & 63, cb = (e >> 9) & 3, kb = e >> 11;
      int k = kb * 32 + ((lane >> 4) << 3) + j;
      int o = cb * 16 + (lane & 15);
      ((unsigned short*)ws)[i] = f2bf(src[o * stride + coff + k]);
    } else {
      int f = i - 40960; float v;
      if (f < 1152){
        int grp = f / 192, rem = f % 192, d = rem >> 6, o = rem & 63;
        if      (grp == 0) v = w10[o*138 + d]     - w10[o*138 + 6 + d];
        else if (grp == 1) v = w10[o*138 + 3 + d] + w10[o*138 + 6 + d];
        else if (grp == 2) v = wx1[o*10 + d]      - wx1[o*10 + 6 + d];
        else if (grp == 3) v = wx1[o*10 + 3 + d]  + wx1[o*10 + 6 + d];
        else if (grp == 4) v = wx2[o*10 + d]      - wx2[o*10 + 6 + d];
        else               v = wx2[o*10 + 3 + d]  + wx2[o*10 + 6 + d];
      }
      else if (f < 1216) v = w10[(f - 1152)*138 + 9];
      else if (f < 1280) v = wx1[(f - 1216)*10  + 9];
      else               v = wx2[(f - 1280)*10  + 9];
      ((float*)(ws + WS_F32))[f] = v;
    }
  }
}

__global__ __launch_bounds__(TPB, 2) void cvkernel(
    const float* __restrict__ xyz1, const float* __restrict__ feat1,
    const float* __restrict__ xyz2, const float* __restrict__ feat2,
    const float* __restrict__ b10v, const float* __restrict__ bx1v,
    const float* __restrict__ b11v, const float* __restrict__ b20v,
    const float* __restrict__ b21v, const float* __restrict__ bx2v,
    const float* __restrict__ b30v, const float* __restrict__ b31v,
    const char*  __restrict__ ws,   float* __restrict__ out)
{
  extern __shared__ __align__(16) char smem[];
  const int tid  = threadIdx.x;
  const int lane = tid & 63;
  const int wave = tid >> 6;
  const int l15  = lane & 15;
  const int lg   = lane >> 4;
  const int tile = blockIdx.x;
  const int b    = tile >> 8;
  const int s0   = (tile & 255) << 5;

  float* x1    = (float*)(smem + OFF_X1);
  float* x2    = (float*)(smem + OFF_X2);
  float* a1f   = (float*)(smem + OFF_A1F);
  float* a2f   = (float*)(smem + OFF_A2F);
  float* c1f   = (float*)(smem + OFF_C1F);
  float* c2f   = (float*)(smem + OFF_C2F);
  float* outb  = (float*)(smem + OFF_OUTB);
  char*  aggB  = smem + OFF_AGGB;
  const float* cw = (const float*)(ws + WS_F32);

  char* myA = smem + OFF_ACT + wave * 8192;
  char* myB = myA + 4096;

  // ---- stage inputs into LDS ----
  if (tid < 32){
#pragma unroll
    for (int d = 0; d < 3; ++d) x1[tid*4+d] = xyz1[(b*3+d)*S_LEN + s0 + tid];
    x1[tid*4+3] = 0.f;
  } else if (tid < 64){
    int p = tid - 32;
#pragma unroll
    for (int d = 0; d < 3; ++d) x2[p*4+d] = xyz2[(b*3+d)*S_LEN + s0 + p];
    x2[p*4+3] = 0.f;
  }
  for (int i = tid; i < 2048; i += TPB){
    int ch = i >> 5, p = i & 31;
    stBF(smem + OFF_F1B, p, ch, feat1[(b*64+ch)*S_LEN + s0 + p]);
    stBF(smem + OFF_F2B, p, ch, feat2[(b*64+ch)*S_LEN + s0 + p]);
  }
  __syncthreads();

  // ---- per-point precompute: a1 = Wf1*f1, a2 = Wf2*f2 (MFMA) ----
  {
    const char* Ab  = (wave < 2) ? (smem + OFF_F1B) : (smem + OFF_F2B);
    const char* Bg  = ws + ((wave < 2) ? WS_WF1 : WS_WF2);
    float* dstf     = (wave < 2) ? a1f : a2f;
    const int rt    = wave & 1;
    f32x4 acc[4];
#pragma unroll
    for (int cb = 0; cb < 4; ++cb) acc[cb] = (f32x4){0.f,0.f,0.f,0.f};
    gemm_k64(acc, Ab, Bg, rt * 16, lane);
#pragma unroll
    for (int cb = 0; cb < 4; ++cb)
#pragma unroll
      for (int v = 0; v < 4; ++v){
        int row = rt*16 + (lg << 2) + v;
        int col = (cb << 4) + l15;
        dstf[row*64 + col] = acc[cb][v];
      }
  }
  __syncthreads();
  // x-parts (K=3), comb read from global (L2-hot)
  for (int i = tid; i < 2048; i += TPB){
    int o = i & 63, p = i >> 6;
    float xa = x1[p*4], xb = x1[p*4+1], xc = x1[p*4+2];
    float ya = x2[p*4], yb = x2[p*4+1], yc = x2[p*4+2];
    a1f[p*64+o] += cw[      o]*xa + cw[ 64+o]*xb + cw[128+o]*xc;
    a2f[p*64+o] += cw[192+  o]*ya + cw[256+o]*yb + cw[320+o]*yc;
    c1f[p*64+o]  = cw[384+  o]*xa + cw[448+o]*xb + cw[512+o]*xc;
    c2f[p*64+o]  = cw[576+  o]*ya + cw[640+o]*yb + cw[704+o]*yc;
  }
  __syncthreads();

  // per-lane constants (global reads, L2-hot)
  const int myc4 = l15 << 2;
  const float4v we4 = *(const float4v*)(cw + 1152 + myc4);
  const float4v ee4 = *(const float4v*)(cw + 1216 + myc4);
  const float4v ge4 = *(const float4v*)(cw + 1280 + myc4);
  const float4v b04 = *(const float4v*)(b10v + myc4);
  const float4v b14 = *(const float4v*)(bx1v + myc4);
  const float4v b54 = *(const float4v*)(bx2v + myc4);
  float b11r[4], b20r[4], b21r[4], b30r[4], b31r[4];
#pragma unroll
  for (int cb = 0; cb < 4; ++cb){
    b11r[cb] = b11v[cb*16 + l15];
    b20r[cb] = b20v[cb*16 + l15];
    b21r[cb] = b21v[cb*16 + l15];
    b30r[cb] = b30v[cb*16 + l15];
    b31r[cb] = b31v[cb*16 + l15];
  }

  bf16x8 BW1[8], BW2[8];
  load_B8(BW1, ws + WSO_L11, lane);
  load_B8(BW2, ws + WSO_L21, lane);

  // ================= stage 1: 8 wave-local chunks, no barriers ============
  for (int cc = 0; cc < 8; ++cc){
    const int p  = wave*8 + cc;
    // issue W20 loads early; consumed after mlp1_1 (L2 latency hidden)
    bf16x8 B20a[8], B20b[8];
    load_B8(B20a, ws + WSO_L20,        lane);
    load_B8(B20b, ws + WSO_L20 + 8192, lane);

    const float px = x1[p*4], py = x1[p*4+1], pz = x1[p*4+2];
    const float4v A1 = *(const float4v*)(a1f + p*64 + myc4);
    const float4v C1 = *(const float4v*)(c1f + p*64 + myc4);
    // build h1 -> myA, e -> myB (wave's 32 rows)
#pragma unroll
    for (int it = 0; it < 8; ++it){
      int q = it*4 + lg;
      float dx = x2[q*4]-px, dy = x2[q*4+1]-py, dz = x2[q*4+2]-pz;
      float eu = sqrtf(dx*dx + dy*dy + dz*dz + 1e-20f);
      float4v A2 = *(const float4v*)(a2f + q*64 + myc4);
      float4v C2 = *(const float4v*)(c2f + q*64 + myc4);
      float4v hv = A1 + A2 + we4*eu + b04;
      float4v ev = C1 + C2 + ee4*eu + b14;
      hv.x = fmaxf(hv.x,0.f); hv.y = fmaxf(hv.y,0.f); hv.z = fmaxf(hv.z,0.f); hv.w = fmaxf(hv.w,0.f);
      ev.x = fmaxf(ev.x,0.f); ev.y = fmaxf(ev.y,0.f); ev.z = fmaxf(ev.z,0.f); ev.w = fmaxf(ev.w,0.f);
      stBF4(myA, q, myc4, hv);
      stBF4(myB, q, myc4, ev);
    }
    // mlp1_1: h2 = relu(W11*h1 + b11) -> overwrite myA (h1 dead)
    f32x4 acc[2][4];
#pragma unroll
    for (int t = 0; t < 2; ++t)
#pragma unroll
      for (int cb = 0; cb < 4; ++cb) acc[t][cb] = (f32x4){0.f,0.f,0.f,0.f};
    gemm32_k64(acc, myA, BW1, lane);
    float h2r[2][4][4];
#pragma unroll
    for (int t = 0; t < 2; ++t)
#pragma unroll
      for (int cb = 0; cb < 4; ++cb)
#pragma unroll
        for (int v = 0; v < 4; ++v){
          float h = fmaxf(acc[t][cb][v] + b11r[cb], 0.f);
          h2r[t][cb][v] = h;
          stBF(myA, t*16 + (lg<<2) + v, (cb<<4) + l15, h);
        }
    // mlp2_0: K=128 over [e(myB); h2(myA)] -> overwrite myB (e dead)
#pragma unroll
    for (int t = 0; t < 2; ++t)
#pragma unroll
      for (int cb = 0; cb < 4; ++cb) acc[t][cb] = (f32x4){0.f,0.f,0.f,0.f};
    gemm32_k64(acc, myB, B20a, lane);
    gemm32_k64(acc, myA, B20b, lane);
#pragma unroll
    for (int t = 0; t < 2; ++t)
#pragma unroll
      for (int cb = 0; cb < 4; ++cb)
#pragma unroll
        for (int v = 0; v < 4; ++v)
          stBF(myB, t*16 + (lg<<2) + v, (cb<<4) + l15,
               fmaxf(acc[t][cb][v] + b20r[cb], 0.f));
    // mlp2_1: logits in regs
#pragma unroll
    for (int t = 0; t < 2; ++t)
#pragma unroll
      for (int cb = 0; cb < 4; ++cb) acc[t][cb] = (f32x4){0.f,0.f,0.f,0.f};
    gemm32_k64(acc, myB, BW2, lane);
    // register softmax over the 32 q-rows + aggregation with f32 h2
    float mm[4], den[4], num[4];
#pragma unroll
    for (int cb = 0; cb < 4; ++cb) mm[cb] = -1e30f;
#pragma unroll
    for (int t = 0; t < 2; ++t)
#pragma unroll
      for (int cb = 0; cb < 4; ++cb)
#pragma unroll
        for (int v = 0; v < 4; ++v){
          float l = fmaxf(acc[t][cb][v] + b21r[cb], 0.f);
          acc[t][cb][v] = l;
          mm[cb] = fmaxf(mm[cb], l);
        }
#pragma unroll
    for (int cb = 0; cb < 4; ++cb){ mm[cb] = red_max(mm[cb]); den[cb] = 0.f; num[cb] = 0.f; }
#pragma unroll
    for (int t = 0; t < 2; ++t)
#pragma unroll
      for (int cb = 0; cb < 4; ++cb)
#pragma unroll
        for (int v = 0; v < 4; ++v){
          float e = __expf(acc[t][cb][v] - mm[cb]);
          den[cb] += e;
          num[cb] += e * h2r[t][cb][v];
        }
#pragma unroll
    for (int cb = 0; cb < 4; ++cb){ den[cb] = red_sum(den[cb]); num[cb] = red_sum(num[cb]); }
    if (lane < 16){
#pragma unroll
      for (int cb = 0; cb < 4; ++cb)
        stBF(aggB, p, (cb<<4) + lane, num[cb] / den[cb]);
    }
  }
  __syncthreads();

  // ---- stage-2 per-point precompute: d1/d2 (K=3), v1/v2 (MFMA) ----
  for (int i = tid; i < 2048; i += TPB){
    int o = i & 63, p = i >> 6;
    float xa = x1[p*4], xb = x1[p*4+1], xc = x1[p*4+2];
    c1f[p*64+o] = cw[768+o]*xa + cw[832+o]*xb + cw[896+o]*xc;
    c2f[p*64+o] = cw[960+o]*xa + cw[1024+o]*xb + cw[1088+o]*xc;
  }
  {
    const char* Ab = (wave < 2) ? (smem + OFF_F1B) : aggB;
    const char* Bg = ws + ((wave < 2) ? WS_W30B : WS_W30C);
    float* dstf    = (wave < 2) ? a1f : a2f;   // v1 / v2
    const int rt   = wave & 1;
    f32x4 acc[4];
#pragma unroll
    for (int cb = 0; cb < 4; ++cb) acc[cb] = (f32x4){0.f,0.f,0.f,0.f};
    gemm_k64(acc, Ab, Bg, rt*16, lane);
#pragma unroll
    for (int cb = 0; cb < 4; ++cb)
#pragma unroll
      for (int v = 0; v < 4; ++v){
        int row = rt*16 + (lg << 2) + v;
        int col = (cb << 4) + l15;
        dstf[row*64 + col] = acc[cb][v];
      }
  }
  __syncthreads();

  // ================= stage 2: 8 wave-local chunks, no barriers ============
  load_B8(BW1, ws + WSO_L30A, lane);
  load_B8(BW2, ws + WSO_L31, lane);
  for (int cc = 0; cc < 8; ++cc){
    const int p  = wave*8 + cc;
    const float px = x1[p*4], py = x1[p*4+1], pz = x1[p*4+2];
    const float4v C1 = *(const float4v*)(c1f + p*64 + myc4);
    float v1r[4];
#pragma unroll
    for (int cb = 0; cb < 4; ++cb) v1r[cb] = a1f[p*64 + (cb<<4) + l15];
    // e2 -> myA
#pragma unroll
    for (int it = 0; it < 8; ++it){
      int q = it*4 + lg;
      float dx = x1[q*4]-px, dy = x1[q*4+1]-py, dz = x1[q*4+2]-pz;
      float eu = sqrtf(dx*dx + dy*dy + dz*dz + 1e-20f);
      float4v C2 = *(const float4v*)(c2f + q*64 + myc4);
      float4v ev = C1 + C2 + ge4*eu + b54;
      ev.x = fmaxf(ev.x,0.f); ev.y = fmaxf(ev.y,0.f); ev.z = fmaxf(ev.z,0.f); ev.w = fmaxf(ev.w,0.f);
      stBF4(myA, q, myc4, ev);
    }
    // mlp3_0: c3 = relu(W30a*e2 + v1[p] + v2[q] + b30) -> myB
    f32x4 acc[2][4];
#pragma unroll
    for (int t = 0; t < 2; ++t)
#pragma unroll
      for (int cb = 0; cb < 4; ++cb) acc[t][cb] = (f32x4){0.f,0.f,0.f,0.f};
    gemm32_k64(acc, myA, BW1, lane);
#pragma unroll
    for (int t = 0; t < 2; ++t)
#pragma unroll
      for (int cb = 0; cb < 4; ++cb)
#pragma unroll
        for (int v = 0; v < 4; ++v){
          int q = t*16 + (lg<<2) + v;
          int col = (cb<<4) + l15;
          float c3 = acc[t][cb][v] + v1r[cb] + a2f[q*64+col] + b30r[cb];
          stBF(myB, q, col, fmaxf(c3, 0.f));
        }
    // mlp3_1: logits in regs
#pragma unroll
    for (int t = 0; t < 2; ++t)
#pragma unroll
      for (int cb = 0; cb < 4; ++cb) acc[t][cb] = (f32x4){0.f,0.f,0.f,0.f};
    gemm32_k64(acc, myB, BW2, lane);
    // masked register softmax (q != p) + output
    float mm[4], den[4], num[4];
#pragma unroll
    for (int cb = 0; cb < 4; ++cb) mm[cb] = -1e30f;
#pragma unroll
    for (int t = 0; t < 2; ++t)
#pragma unroll
      for (int cb = 0; cb < 4; ++cb)
#pragma unroll
        for (int v = 0; v < 4; ++v){
          int q = t*16 + (lg<<2) + v;
          float l = fmaxf(acc[t][cb][v] + b31r[cb], 0.f);
          l = (q == p) ? -1e30f : l;
          acc[t][cb][v] = l;
          mm[cb] = fmaxf(mm[cb], l);
        }
#pragma unroll
    for (int cb = 0; cb < 4; ++cb){ mm[cb] = red_max(mm[cb]); den[cb] = 0.f; num[cb] = 0.f; }
#pragma unroll
    for (int t = 0; t < 2; ++t)
#pragma unroll
      for (int cb = 0; cb < 4; ++cb)
#pragma unroll
        for (int v = 0; v < 4; ++v){
          int q = t*16 + (lg<<2) + v;
          float e = __expf(acc[t][cb][v] - mm[cb]);   // exp(-1e30-m)=0 masks q==p
          den[cb] += e;
          num[cb] += e * ldBF(aggB, q, (cb<<4) + l15);
        }
#pragma unroll
    for (int cb = 0; cb < 4; ++cb){ den[cb] = red_sum(den[cb]); num[cb] = red_sum(num[cb]); }
    if (lane < 16){
#pragma unroll
      for (int cb = 0; cb < 4; ++cb)
        outb[outb_idx(p, (cb<<4) + lane)] = num[cb] / den[cb];
    }
  }
  __syncthreads();

  // coalesced output write (OUTB is XOR-swizzled f32)
  for (int i = tid; i < 2048; i += TPB){
    int ch = i >> 5, p = i & 31;
    out[(b*64 + ch)*S_LEN + s0 + p] = outb[outb_idx(p, ch)];
  }
}

extern "C" void kernel_launch(void* const* d_in, const int* in_sizes, int n_in,
                              void* d_out, int out_size, void* d_ws, size_t ws_size,
                              hipStream_t stream)
{
  const float* xyz1 = (const float*)d_in[0];
  const float* feat1= (const float*)d_in[1];
  const float* xyz2 = (const float*)d_in[2];
  const float* feat2= (const float*)d_in[3];
  const float* w10  = (const float*)d_in[4];
  const float* b10  = (const float*)d_in[5];
  const float* w11  = (const float*)d_in[6];
  const float* b11  = (const float*)d_in[7];
  const float* wx1  = (const float*)d_in[8];
  const float* bx1  = (const float*)d_in[9];
  const float* wx2  = (const float*)d_in[10];
  const float* bx2  = (const float*)d_in[11];
  const float* w20  = (const float*)d_in[12];
  const float* b20  = (const float*)d_in[13];
  const float* w21  = (const float*)d_in[14];
  const float* b21  = (const float*)d_in[15];
  const float* w30  = (const float*)d_in[16];
  const float* b30  = (const float*)d_in[17];
  const float* w31  = (const float*)d_in[18];
  const float* b31  = (const float*)d_in[19];

  (void)hipFuncSetAttribute(reinterpret_cast<const void*>(cvkernel),
                            hipFuncAttributeMaxDynamicSharedMemorySize, LDS_TOTAL);

  hipLaunchKernelGGL(pack_weights, dim3(64), dim3(256), 0, stream,
                     w10, w11, wx1, wx2, w20, w21, w30, w31, (unsigned char*)d_ws);
  hipLaunchKernelGGL(cvkernel, dim3(512), dim3(TPB), LDS_TOTAL, stream,
                     xyz1, feat1, xyz2, feat2,
                     b10, bx1, b11, b20, b21, bx2, b30, b31,
                     (const char*)d_ws, (float*)d_out);
}